// Round 1
// baseline (2522.006 us; speedup 1.0000x reference)
//
#include <hip/hip_runtime.h>
#include <hip/hip_bf16.h>

// Multi-relational GCN, 4 layers on MI355X.
// Layer = per-relation dense transform XW[r] = H[j(r)] @ W[r], then
// edge scatter out[i(r)][row] += val * XW[r][col], i(r)=r>>1, j(r)=r&1.
// Layers 1-2 use adj1, layers 3-4 use adj2. ReLU after layers 1-3 is folded
// into the next layer's GEMM load. Final layer has no ReLU.

#define DOUT 64  // hidden/output width (W shapes are [4, d_in, 64])

// ---------------- dense transform: XW[r][n][c] = sum_k H[j][n][k] W[r][k][c]
__global__ __launch_bounds__(256) void gemm_xw(
    const float* __restrict__ H,   // [2, N, d_in]
    const float* __restrict__ W,   // [4, d_in, 64]
    float* __restrict__ XW,        // [4, N, 64]
    int N, int d_in, int relu_in)
{
    const int r  = blockIdx.y;          // relation 0..3
    const int j  = r & 1;               // source node type
    const int c  = threadIdx.x & 63;    // output column
    const int rl = threadIdx.x >> 6;    // row within block (0..3)
    const int row = blockIdx.x * 4 + rl;

    extern __shared__ float wlds[];     // [d_in][64]
    const float* wsrc = W + (size_t)r * d_in * DOUT;
    for (int idx = threadIdx.x; idx < d_in * DOUT; idx += 256)
        wlds[idx] = wsrc[idx];
    __syncthreads();

    if (row >= N) return;

    const float* h = H + ((size_t)j * N + row) * d_in;
    float acc = 0.f;
    for (int k = 0; k < d_in; k += 4) {
        float4 h4 = *reinterpret_cast<const float4*>(h + k);
        if (relu_in) {
            h4.x = fmaxf(h4.x, 0.f); h4.y = fmaxf(h4.y, 0.f);
            h4.z = fmaxf(h4.z, 0.f); h4.w = fmaxf(h4.w, 0.f);
        }
        acc += h4.x * wlds[(k + 0) * DOUT + c];
        acc += h4.y * wlds[(k + 1) * DOUT + c];
        acc += h4.z * wlds[(k + 2) * DOUT + c];
        acc += h4.w * wlds[(k + 3) * DOUT + c];
    }
    XW[(((size_t)r * N) + row) * DOUT + c] = acc;
}

// ---------------- edge scatter: one wave per edge, lane l = column l
__global__ __launch_bounds__(256) void scatter_add(
    const int*   __restrict__ rows,  // [4, E]
    const int*   __restrict__ cols,  // [4, E]
    const float* __restrict__ vals,  // [4, E]
    const float* __restrict__ XW,    // [4, N, 64]
    float*       __restrict__ out,   // [2, N, 64]
    int N, int E)
{
    const int r    = blockIdx.y;
    const int e    = blockIdx.x * 4 + (threadIdx.x >> 6);
    const int lane = threadIdx.x & 63;
    if (e >= E) return;

    const size_t idx = (size_t)r * E + e;
    const int   row = rows[idx];
    const int   col = cols[idx];
    const float v   = vals[idx];

    const float x = XW[(((size_t)r * N) + col) * DOUT + lane];
    atomicAdd(&out[(((size_t)(r >> 1) * N) + row) * DOUT + lane], v * x);
}

extern "C" void kernel_launch(void* const* d_in, const int* in_sizes, int n_in,
                              void* d_out, int out_size, void* d_ws, size_t ws_size,
                              hipStream_t stream) {
    const float* feat      = (const float*)d_in[0];
    const int*   adj1_rows = (const int*)  d_in[1];
    const int*   adj1_cols = (const int*)  d_in[2];
    const float* adj1_vals = (const float*)d_in[3];
    const int*   adj2_rows = (const int*)  d_in[4];
    const int*   adj2_cols = (const int*)  d_in[5];
    const float* adj2_vals = (const float*)d_in[6];
    const float* W1        = (const float*)d_in[7];
    const float* W2        = (const float*)d_in[8];
    const float* W3        = (const float*)d_in[9];
    const float* W4        = (const float*)d_in[10];

    const int E = in_sizes[1] / 4;                 // 500000
    const int F = in_sizes[7] / (4 * DOUT);        // 128
    const int N = in_sizes[0] / (2 * F);           // 50000

    float* XW = (float*)d_ws;                      // [4, N, 64]
    float* Ha = XW + (size_t)4 * N * DOUT;         // [2, N, 64]
    float* out = (float*)d_out;                    // [2, N, 64]

    const size_t hbytes = (size_t)2 * N * DOUT * sizeof(float);

    dim3 gemm_grid((N + 3) / 4, 4);
    dim3 scat_grid((E + 3) / 4, 4);
    const int bs = 256;

    // ---- layer 1: feat (d_in=F, no relu) on adj1 -> Ha
    gemm_xw<<<gemm_grid, bs, F * DOUT * sizeof(float), stream>>>(feat, W1, XW, N, F, 0);
    hipMemsetAsync(Ha, 0, hbytes, stream);
    scatter_add<<<scat_grid, bs, 0, stream>>>(adj1_rows, adj1_cols, adj1_vals, XW, Ha, N, E);

    // ---- layer 2: relu(Ha) (d_in=64) on adj1 -> d_out (scratch use)
    gemm_xw<<<gemm_grid, bs, DOUT * DOUT * sizeof(float), stream>>>(Ha, W2, XW, N, DOUT, 1);
    hipMemsetAsync(out, 0, hbytes, stream);
    scatter_add<<<scat_grid, bs, 0, stream>>>(adj1_rows, adj1_cols, adj1_vals, XW, out, N, E);

    // ---- layer 3: relu(d_out) (d_in=64) on adj2 -> Ha
    gemm_xw<<<gemm_grid, bs, DOUT * DOUT * sizeof(float), stream>>>(out, W3, XW, N, DOUT, 1);
    hipMemsetAsync(Ha, 0, hbytes, stream);
    scatter_add<<<scat_grid, bs, 0, stream>>>(adj2_rows, adj2_cols, adj2_vals, XW, Ha, N, E);

    // ---- layer 4: relu(Ha) (d_in=64) on adj2 -> d_out (final, no relu)
    gemm_xw<<<gemm_grid, bs, DOUT * DOUT * sizeof(float), stream>>>(Ha, W4, XW, N, DOUT, 1);
    hipMemsetAsync(out, 0, hbytes, stream);
    scatter_add<<<scat_grid, bs, 0, stream>>>(adj2_rows, adj2_cols, adj2_vals, XW, out, N, E);
}

// Round 2
// 1723.527 us; speedup vs baseline: 1.4633x; 1.4633x over previous
//
#include <hip/hip_runtime.h>
#include <hip/hip_bf16.h>

// Multi-relational GCN, 4 layers.
// Round 2: CSR-ized scatter (no float atomics) + register-tiled GEMM (no LDS).
// relation r = 2*i + j: dst type i = r>>1, src type j = r&1.
// Layers 1-2 use adj1 (segments 0..3), layers 3-4 use adj2 (segments 4..7).

#define DOUT 64

// ---------------- histogram of dst rows into cnt[r*N + row]
__global__ __launch_bounds__(256) void k_hist(
    const int* __restrict__ rows, int E, int N, int* __restrict__ cnt)
{
    const int r = blockIdx.y;
    const int e = blockIdx.x * 256 + threadIdx.x;
    if (e < E) atomicAdd(&cnt[r * N + rows[(size_t)r * E + e]], 1);
}

// ---------------- exclusive scan, 3-kernel (block scan / partials scan / add)
__global__ __launch_bounds__(256) void k_scan1(
    const int* __restrict__ cnt, int M, int* __restrict__ out, int* __restrict__ partials)
{
    __shared__ int s[256];
    const int i = blockIdx.x * 256 + threadIdx.x;
    const int x = (i < M) ? cnt[i] : 0;
    s[threadIdx.x] = x;
    __syncthreads();
    for (int off = 1; off < 256; off <<= 1) {
        int t = (threadIdx.x >= off) ? s[threadIdx.x - off] : 0;
        __syncthreads();
        s[threadIdx.x] += t;
        __syncthreads();
    }
    if (i < M) out[i] = s[threadIdx.x] - x;  // exclusive
    if (threadIdx.x == 255) partials[blockIdx.x] = s[255];
}

__global__ __launch_bounds__(256) void k_scan2(int* __restrict__ partials, int nb)
{
    __shared__ int s[256];
    __shared__ int carry_s;
    if (threadIdx.x == 0) carry_s = 0;
    __syncthreads();
    for (int base = 0; base < nb; base += 256) {
        const int i = base + threadIdx.x;
        const int x = (i < nb) ? partials[i] : 0;
        s[threadIdx.x] = x;
        __syncthreads();
        for (int off = 1; off < 256; off <<= 1) {
            int t = (threadIdx.x >= off) ? s[threadIdx.x - off] : 0;
            __syncthreads();
            s[threadIdx.x] += t;
            __syncthreads();
        }
        const int carry = carry_s;
        const int incl  = s[threadIdx.x];
        __syncthreads();
        if (i < nb) partials[i] = incl - x + carry;
        if (threadIdx.x == 255) carry_s = carry + incl;
        __syncthreads();
    }
}

__global__ __launch_bounds__(256) void k_scan3(
    int* __restrict__ row_ptr, int* __restrict__ cursor,
    const int* __restrict__ partials, int M, int total)
{
    const int i = blockIdx.x * 256 + threadIdx.x;
    if (i < M) {
        const int v = row_ptr[i] + partials[blockIdx.x];
        row_ptr[i] = v;
        cursor[i]  = v;
    }
    if (i == 0) row_ptr[M] = total;
}

// ---------------- CSR fill: (col, val) pairs at scanned positions
__global__ __launch_bounds__(256) void k_fill(
    const int* __restrict__ rows, const int* __restrict__ cols,
    const float* __restrict__ vals, int E, int N,
    int* __restrict__ cursor, int2* __restrict__ cv)
{
    const int r = blockIdx.y;
    const int e = blockIdx.x * 256 + threadIdx.x;
    if (e >= E) return;
    const size_t idx = (size_t)r * E + e;
    const int row = rows[idx];
    const int pos = atomicAdd(&cursor[r * N + row], 1);
    cv[pos] = make_int2(cols[idx], __float_as_int(vals[idx]));
}

// ---------------- dense transform, register-tiled, no LDS
// XW[n][c] = sum_k relu?(H[n][k]) * W[k][c]; 8 rows per thread, 32 rows/block.
template<int RELU>
__global__ __launch_bounds__(256) void k_gemm(
    const float* __restrict__ H,   // [N, d_in] (pre-offset to src type)
    const float* __restrict__ W,   // [d_in, 64] (pre-offset to relation)
    float* __restrict__ XW,        // [N, 64]
    int N, int d_in)
{
    const int c    = threadIdx.x & 63;
    const int rl   = threadIdx.x >> 6;
    const int row0 = blockIdx.x * 32 + rl;

    int rowc[8];
#pragma unroll
    for (int m = 0; m < 8; ++m) {
        int row = row0 + m * 4;
        rowc[m] = (row < N) ? row : (N - 1);
    }

    float acc[8];
#pragma unroll
    for (int m = 0; m < 8; ++m) acc[m] = 0.f;

#pragma unroll 4
    for (int k = 0; k < d_in; k += 4) {
        const float w0 = W[(k + 0) * DOUT + c];
        const float w1 = W[(k + 1) * DOUT + c];
        const float w2 = W[(k + 2) * DOUT + c];
        const float w3 = W[(k + 3) * DOUT + c];
#pragma unroll
        for (int m = 0; m < 8; ++m) {
            float4 h4 = *reinterpret_cast<const float4*>(H + (size_t)rowc[m] * d_in + k);
            if (RELU) {
                h4.x = fmaxf(h4.x, 0.f); h4.y = fmaxf(h4.y, 0.f);
                h4.z = fmaxf(h4.z, 0.f); h4.w = fmaxf(h4.w, 0.f);
            }
            acc[m] = fmaf(h4.x, w0, fmaf(h4.y, w1, fmaf(h4.z, w2, fmaf(h4.w, w3, acc[m]))));
        }
    }

#pragma unroll
    for (int m = 0; m < 8; ++m) {
        const int row = row0 + m * 4;
        if (row < N) XW[(size_t)row * DOUT + c] = acc[m];
    }
}

// ---------------- CSR SpMM: one wave per dst row, lane = column, no atomics
__global__ __launch_bounds__(256) void k_spmm(
    const int*  __restrict__ row_ptr,  // pre-offset to segment, sentinel valid
    const int2* __restrict__ cv,       // global (col,val) array
    const float* __restrict__ XW,      // [N, 64]
    float* __restrict__ out,           // [N, 64] (pre-offset to dst type)
    int N, int beta)
{
    const int n    = blockIdx.x * 4 + (threadIdx.x >> 6);
    const int lane = threadIdx.x & 63;
    if (n >= N) return;

    const int s = row_ptr[n];
    const int e = row_ptr[n + 1];

    float acc = beta ? out[(size_t)n * DOUT + lane] : 0.f;

    int t = s;
    for (; t + 1 < e; t += 2) {
        const int2 p0 = cv[t];
        const int2 p1 = cv[t + 1];
        const float x0 = XW[(size_t)p0.x * DOUT + lane];
        const float x1 = XW[(size_t)p1.x * DOUT + lane];
        acc = fmaf(__int_as_float(p0.y), x0, acc);
        acc = fmaf(__int_as_float(p1.y), x1, acc);
    }
    if (t < e) {
        const int2 p = cv[t];
        acc = fmaf(__int_as_float(p.y), XW[(size_t)p.x * DOUT + lane], acc);
    }

    out[(size_t)n * DOUT + lane] = acc;
}

extern "C" void kernel_launch(void* const* d_in, const int* in_sizes, int n_in,
                              void* d_out, int out_size, void* d_ws, size_t ws_size,
                              hipStream_t stream) {
    const float* feat      = (const float*)d_in[0];
    const int*   adj1_rows = (const int*)  d_in[1];
    const int*   adj1_cols = (const int*)  d_in[2];
    const float* adj1_vals = (const float*)d_in[3];
    const int*   adj2_rows = (const int*)  d_in[4];
    const int*   adj2_cols = (const int*)  d_in[5];
    const float* adj2_vals = (const float*)d_in[6];
    const float* W1        = (const float*)d_in[7];
    const float* W2        = (const float*)d_in[8];
    const float* W3        = (const float*)d_in[9];
    const float* W4        = (const float*)d_in[10];

    const int E = in_sizes[1] / 4;              // 500000
    const int F = in_sizes[7] / (4 * DOUT);     // 128
    const int N = in_sizes[0] / (2 * F);        // 50000
    const int M = 8 * N;                        // total histogram bins
    const int nb1 = (M + 255) / 256;

    // ---- workspace layout (≈73.6 MB)
    float* ws = (float*)d_ws;
    size_t off = 0;
    float* XW      = ws + off; off += (size_t)N * DOUT;          // 12.8 MB
    float* Ha      = ws + off; off += (size_t)2 * N * DOUT;      // 25.6 MB
    int2*  cv      = (int2*)(ws + off); off += (size_t)8 * E * 2; // 32 MB
    int*   row_ptr = (int*)(ws + off);  off += (size_t)M + 1;     // 1.6 MB
    int*   cursor  = (int*)(ws + off);  off += (size_t)M;         // 1.6 MB
    int*   partials= (int*)(ws + off);  off += (size_t)nb1 + 8;
    float* out     = (float*)d_out;

    const dim3 egrid((E + 255) / 256, 4);

    // ---- build CSR for both adjacency sets (segments 0..3 = adj1, 4..7 = adj2)
    hipMemsetAsync(cursor, 0, (size_t)M * sizeof(int), stream);
    k_hist<<<egrid, 256, 0, stream>>>(adj1_rows, E, N, cursor);
    k_hist<<<egrid, 256, 0, stream>>>(adj2_rows, E, N, cursor + 4 * N);
    k_scan1<<<nb1, 256, 0, stream>>>(cursor, M, row_ptr, partials);
    k_scan2<<<1, 256, 0, stream>>>(partials, nb1);
    k_scan3<<<nb1, 256, 0, stream>>>(row_ptr, cursor, partials, M, 8 * E);
    k_fill<<<egrid, 256, 0, stream>>>(adj1_rows, adj1_cols, adj1_vals, E, N, cursor, cv);
    k_fill<<<egrid, 256, 0, stream>>>(adj2_rows, adj2_cols, adj2_vals, E, N, cursor + 4 * N, cv);

    const dim3 ggrid((N + 31) / 32);
    const dim3 sgrid((N + 3) / 4);

    // ---- one layer: for each dst type i, relation pair (2i, 2i+1); beta on 2nd
    auto layer = [&](const float* Hin, int d_in, int relu, const float* Wl,
                     int set, float* Hout) {
        for (int i = 0; i < 2; ++i) {
            for (int jj = 0; jj < 2; ++jj) {
                const int r   = 2 * i + jj;
                const int seg = set * 4 + r;
                const float* Hsrc = Hin + (size_t)jj * N * d_in;
                const float* Wr   = Wl + (size_t)r * d_in * DOUT;
                if (relu) k_gemm<1><<<ggrid, 256, 0, stream>>>(Hsrc, Wr, XW, N, d_in);
                else      k_gemm<0><<<ggrid, 256, 0, stream>>>(Hsrc, Wr, XW, N, d_in);
                k_spmm<<<sgrid, 256, 0, stream>>>(row_ptr + (size_t)seg * N, cv, XW,
                                                  Hout + (size_t)i * N * DOUT, N, jj);
            }
        }
    };

    layer(feat, F,    0, W1, 0, Ha);   // L1: adj1, no relu on input
    layer(Ha,   DOUT, 1, W2, 0, out);  // L2: adj1
    layer(out,  DOUT, 1, W3, 1, Ha);   // L3: adj2
    layer(Ha,   DOUT, 1, W4, 1, out);  // L4: adj2 (final, no output relu)
}

// Round 3
// 1383.490 us; speedup vs baseline: 1.8229x; 1.2458x over previous
//
#include <hip/hip_runtime.h>
#include <hip/hip_bf16.h>

// Multi-relational GCN, 4 layers. Round 3:
//  - one GEMM launch per layer (128-wide out = [W_j | W_{2+j}] concat, bf16 XW)
//  - one SpMM launch per layer (both relation segments per dst row, no beta)
//  - CSR build: merged hist + merged fill (grid.y = 8 segments)
// relation r = 2*i + j: dst type i = r>>1, src type j = r&1.
// Segments 0..3 = adj1 (layers 1-2), 4..7 = adj2 (layers 3-4).

#define DOUT 64
#define OUTW 128

__device__ __forceinline__ float bf2f(unsigned short u) {
    return __uint_as_float((unsigned)u << 16);
}

// ---------------- histogram of dst rows into cnt[s*N + row], s = 0..7
__global__ __launch_bounds__(256) void k_hist(
    const int* __restrict__ rows1, const int* __restrict__ rows2,
    int E, int N, int* __restrict__ cnt)
{
    const int s = blockIdx.y;
    const int* rows = (s < 4) ? rows1 : rows2;
    const int rl = s & 3;
    const int e = blockIdx.x * 256 + threadIdx.x;
    if (e < E) atomicAdd(&cnt[s * N + rows[(size_t)rl * E + e]], 1);
}

// ---------------- exclusive scan, 3-kernel
__global__ __launch_bounds__(256) void k_scan1(
    const int* __restrict__ cnt, int M, int* __restrict__ out, int* __restrict__ partials)
{
    __shared__ int sm[256];
    const int i = blockIdx.x * 256 + threadIdx.x;
    const int x = (i < M) ? cnt[i] : 0;
    sm[threadIdx.x] = x;
    __syncthreads();
    for (int off = 1; off < 256; off <<= 1) {
        int t = (threadIdx.x >= off) ? sm[threadIdx.x - off] : 0;
        __syncthreads();
        sm[threadIdx.x] += t;
        __syncthreads();
    }
    if (i < M) out[i] = sm[threadIdx.x] - x;
    if (threadIdx.x == 255) partials[blockIdx.x] = sm[255];
}

__global__ __launch_bounds__(256) void k_scan2(int* __restrict__ partials, int nb)
{
    __shared__ int sm[256];
    __shared__ int carry_s;
    if (threadIdx.x == 0) carry_s = 0;
    __syncthreads();
    for (int base = 0; base < nb; base += 256) {
        const int i = base + threadIdx.x;
        const int x = (i < nb) ? partials[i] : 0;
        sm[threadIdx.x] = x;
        __syncthreads();
        for (int off = 1; off < 256; off <<= 1) {
            int t = (threadIdx.x >= off) ? sm[threadIdx.x - off] : 0;
            __syncthreads();
            sm[threadIdx.x] += t;
            __syncthreads();
        }
        const int carry = carry_s;
        const int incl  = sm[threadIdx.x];
        __syncthreads();
        if (i < nb) partials[i] = incl - x + carry;
        if (threadIdx.x == 255) carry_s = carry + incl;
        __syncthreads();
    }
}

__global__ __launch_bounds__(256) void k_scan3(
    int* __restrict__ row_ptr, int* __restrict__ cursor,
    const int* __restrict__ partials, int M, int total)
{
    const int i = blockIdx.x * 256 + threadIdx.x;
    if (i < M) {
        const int v = row_ptr[i] + partials[blockIdx.x];
        row_ptr[i] = v;
        cursor[i]  = v;
    }
    if (i == 0) row_ptr[M] = total;
}

// ---------------- CSR fill: (col, val) pairs at scanned positions (all 8 segs)
__global__ __launch_bounds__(256) void k_fill(
    const int* __restrict__ rows1, const int* __restrict__ cols1, const float* __restrict__ vals1,
    const int* __restrict__ rows2, const int* __restrict__ cols2, const float* __restrict__ vals2,
    int E, int N, int* __restrict__ cursor, int2* __restrict__ cv)
{
    const int s = blockIdx.y;
    const int e = blockIdx.x * 256 + threadIdx.x;
    if (e >= E) return;
    const int rl = s & 3;
    const int* rows = (s < 4) ? rows1 : rows2;
    const int* cols = (s < 4) ? cols1 : cols2;
    const float* vals = (s < 4) ? vals1 : vals2;
    const size_t idx = (size_t)rl * E + e;
    const int row = rows[idx];
    const int pos = atomicAdd(&cursor[s * N + row], 1);
    cv[pos] = make_int2(cols[idx], __float_as_int(vals[idx]));
}

// ---------------- dense transform: XW2[slice][n][0:64] = H_j W_j(dst0),
//                  [64:128] = H_j W_{2+j}(dst1);  bf16 output, register tiled.
// block 256: col = t&63, half = (t>>6)&1 selects weight matrix, rg = t>>7.
template<int RELU>
__global__ __launch_bounds__(256) void k_gemm(
    const float* __restrict__ H,           // [2, N, d_in]
    const float* __restrict__ Wl,          // [4, d_in, 64]
    __hip_bfloat16* __restrict__ XW2,      // [nslice, N, 128]
    int N, int d_in, int joff)
{
    const int slice = blockIdx.y;
    const int j     = joff + slice;        // source node type
    const int col   = threadIdx.x & 63;
    const int half  = (threadIdx.x >> 6) & 1;
    const int rg    = threadIdx.x >> 7;
    const int row0  = blockIdx.x * 16 + rg * 8;

    const float* Hb = H  + (size_t)j * N * d_in;
    const float* Wb = Wl + (size_t)(half ? (2 + j) : j) * d_in * DOUT;

    int rowc[8];
#pragma unroll
    for (int m = 0; m < 8; ++m) {
        int row = row0 + m;
        rowc[m] = (row < N) ? row : (N - 1);
    }

    float acc[8];
#pragma unroll
    for (int m = 0; m < 8; ++m) acc[m] = 0.f;

#pragma unroll 2
    for (int k = 0; k < d_in; k += 4) {
        const float w0 = Wb[(k + 0) * DOUT + col];
        const float w1 = Wb[(k + 1) * DOUT + col];
        const float w2 = Wb[(k + 2) * DOUT + col];
        const float w3 = Wb[(k + 3) * DOUT + col];
#pragma unroll
        for (int m = 0; m < 8; ++m) {
            float4 h4 = *reinterpret_cast<const float4*>(Hb + (size_t)rowc[m] * d_in + k);
            if (RELU) {
                h4.x = fmaxf(h4.x, 0.f); h4.y = fmaxf(h4.y, 0.f);
                h4.z = fmaxf(h4.z, 0.f); h4.w = fmaxf(h4.w, 0.f);
            }
            acc[m] = fmaf(h4.x, w0, fmaf(h4.y, w1, fmaf(h4.z, w2, fmaf(h4.w, w3, acc[m]))));
        }
    }

#pragma unroll
    for (int m = 0; m < 8; ++m) {
        const int row = row0 + m;
        if (row < N)
            XW2[((size_t)slice * N + row) * OUTW + half * DOUT + col] =
                __float2bfloat16(acc[m]);
    }
}

// ---------------- CSR SpMM: one wave per dst row; sums over 1 or 2 segments.
// grid.y = dst type i. two_src: segments set4+2i and set4+2i+1 with XW slices
// 0 and 1; else single segment set4+2i+jsel with XW slice 0 and beta blend.
__global__ __launch_bounds__(256) void k_spmm(
    const int* __restrict__ row_ptr, int set4,
    const int2* __restrict__ cv,
    const unsigned short* __restrict__ XW2,   // bf16 [nslice, N, 128]
    float* __restrict__ out,                  // [2, N, 64]
    int N, int two_src, int jsel, int beta)
{
    const int i    = blockIdx.y;
    const int n    = blockIdx.x * 4 + (threadIdx.x >> 6);
    const int lane = threadIdx.x & 63;
    if (n >= N) return;

    float acc = beta ? out[((size_t)i * N + n) * DOUT + lane] : 0.f;

    const int nsrc = two_src ? 2 : 1;
    for (int js = 0; js < nsrc; ++js) {
        const int seg = set4 + 2 * i + (two_src ? js : jsel);
        const int* rp = row_ptr + (size_t)seg * N;
        const unsigned short* xw = XW2 + (two_src ? (size_t)js * N * OUTW : 0)
                                       + (size_t)i * DOUT + lane;
        const int s = rp[n];
        const int e = rp[n + 1];

        int t = s;
        for (; t + 3 < e; t += 4) {
            const int2 p0 = cv[t + 0];
            const int2 p1 = cv[t + 1];
            const int2 p2 = cv[t + 2];
            const int2 p3 = cv[t + 3];
            const float x0 = bf2f(xw[(size_t)p0.x * OUTW]);
            const float x1 = bf2f(xw[(size_t)p1.x * OUTW]);
            const float x2 = bf2f(xw[(size_t)p2.x * OUTW]);
            const float x3 = bf2f(xw[(size_t)p3.x * OUTW]);
            acc = fmaf(__int_as_float(p0.y), x0, acc);
            acc = fmaf(__int_as_float(p1.y), x1, acc);
            acc = fmaf(__int_as_float(p2.y), x2, acc);
            acc = fmaf(__int_as_float(p3.y), x3, acc);
        }
        for (; t < e; ++t) {
            const int2 p = cv[t];
            acc = fmaf(__int_as_float(p.y), bf2f(xw[(size_t)p.x * OUTW]), acc);
        }
    }

    out[((size_t)i * N + n) * DOUT + lane] = acc;
}

extern "C" void kernel_launch(void* const* d_in, const int* in_sizes, int n_in,
                              void* d_out, int out_size, void* d_ws, size_t ws_size,
                              hipStream_t stream) {
    const float* feat      = (const float*)d_in[0];
    const int*   adj1_rows = (const int*)  d_in[1];
    const int*   adj1_cols = (const int*)  d_in[2];
    const float* adj1_vals = (const float*)d_in[3];
    const int*   adj2_rows = (const int*)  d_in[4];
    const int*   adj2_cols = (const int*)  d_in[5];
    const float* adj2_vals = (const float*)d_in[6];
    const float* W1        = (const float*)d_in[7];
    const float* W2        = (const float*)d_in[8];
    const float* W3        = (const float*)d_in[9];
    const float* W4        = (const float*)d_in[10];

    const int E = in_sizes[1] / 4;              // 500000
    const int F = in_sizes[7] / (4 * DOUT);     // 128
    const int N = in_sizes[0] / (2 * F);        // 50000
    const int M = 8 * N;
    const int nb1 = (M + 255) / 256;

    // ---- workspace layout; big path needs ~86.4 MB, small path ~73.6 MB
    const size_t xw_big   = (size_t)2 * N * OUTW * sizeof(__hip_bfloat16);
    const size_t xw_small = (size_t)1 * N * OUTW * sizeof(__hip_bfloat16);
    const size_t ha_b     = (size_t)2 * N * DOUT * sizeof(float);
    const size_t cv_b     = (size_t)8 * E * sizeof(int2);
    const size_t rp_b     = ((size_t)M + 8) * sizeof(int);
    const size_t cur_b    = (size_t)M * sizeof(int);
    const size_t par_b    = ((size_t)nb1 + 8) * sizeof(int);
    const int big = (ws_size >= xw_big + ha_b + cv_b + rp_b + cur_b + par_b) ? 1 : 0;

    char* w = (char*)d_ws;
    __hip_bfloat16* XW2 = (__hip_bfloat16*)w;  w += big ? xw_big : xw_small;
    float* Ha           = (float*)w;           w += ha_b;
    int2*  cv           = (int2*)w;            w += cv_b;
    int*   row_ptr      = (int*)w;             w += rp_b;
    int*   cursor       = (int*)w;             w += cur_b;
    int*   partials     = (int*)w;
    float* out          = (float*)d_out;

    // ---- build CSR (segments 0..3 = adj1, 4..7 = adj2)
    const dim3 egrid((E + 255) / 256, 8);
    hipMemsetAsync(cursor, 0, (size_t)M * sizeof(int), stream);
    k_hist<<<egrid, 256, 0, stream>>>(adj1_rows, adj2_rows, E, N, cursor);
    k_scan1<<<nb1, 256, 0, stream>>>(cursor, M, row_ptr, partials);
    k_scan2<<<1, 256, 0, stream>>>(partials, nb1);
    k_scan3<<<nb1, 256, 0, stream>>>(row_ptr, cursor, partials, M, 8 * E);
    k_fill<<<egrid, 256, 0, stream>>>(adj1_rows, adj1_cols, adj1_vals,
                                      adj2_rows, adj2_cols, adj2_vals,
                                      E, N, cursor, cv);

    const dim3 ggrid_big((N + 15) / 16, 2), ggrid_small((N + 15) / 16, 1);
    const dim3 sgrid((N + 3) / 4, 2);

    auto layer = [&](const float* Hin, int d_in, int relu, const float* Wl,
                     int set4, float* Hout) {
        if (big) {
            if (relu) k_gemm<1><<<ggrid_big, 256, 0, stream>>>(Hin, Wl, XW2, N, d_in, 0);
            else      k_gemm<0><<<ggrid_big, 256, 0, stream>>>(Hin, Wl, XW2, N, d_in, 0);
            k_spmm<<<sgrid, 256, 0, stream>>>(row_ptr, set4, cv,
                                              (const unsigned short*)XW2, Hout, N, 1, 0, 0);
        } else {
            for (int j = 0; j < 2; ++j) {
                if (relu) k_gemm<1><<<ggrid_small, 256, 0, stream>>>(Hin, Wl, XW2, N, d_in, j);
                else      k_gemm<0><<<ggrid_small, 256, 0, stream>>>(Hin, Wl, XW2, N, d_in, j);
                k_spmm<<<sgrid, 256, 0, stream>>>(row_ptr, set4, cv,
                                                  (const unsigned short*)XW2, Hout, N, 0, j, j);
            }
        }
    };

    layer(feat, F,    0, W1, 0, Ha);   // L1: adj1
    layer(Ha,   DOUT, 1, W2, 0, out);  // L2: adj1
    layer(out,  DOUT, 1, W3, 4, Ha);   // L3: adj2
    layer(Ha,   DOUT, 1, W4, 4, out);  // L4: adj2 (final, no relu)
}